// Round 8
// baseline (188.401 us; speedup 1.0000x reference)
//
#include <hip/hip_runtime.h>
#include <stdint.h>

#define D_MODEL 1024
#define NUM_HEADS 16
#define DK 64
#define SEQ 2048
#define BATCH 2
#define MROWS (BATCH * SEQ) /* 4096 */
#define LOG2E 1.4426950408889634f
#define FIXM 14.0f /* static softmax max, base-2 domain */

typedef short bf16x8 __attribute__((ext_vector_type(8)));
typedef float f32x4 __attribute__((ext_vector_type(4)));
typedef float f32x16 __attribute__((ext_vector_type(16)));

__device__ __forceinline__ unsigned short f2bf(float f) { // RNE
    unsigned int u = __float_as_uint(f);
    u = (u + 0x7fffu + ((u >> 16) & 1u)) >> 16;
    return (unsigned short)u;
}
__device__ __forceinline__ float bf2f(unsigned short h) {
    return __uint_as_float(((unsigned int)h) << 16);
}
__device__ __forceinline__ void async16(const void* g, void* l) {
    __builtin_amdgcn_global_load_lds(
        (const __attribute__((address_space(1))) void*)g,
        (__attribute__((address_space(3))) void*)l, 16, 0, 0);
}
__device__ __forceinline__ unsigned int cvtpk(float lo, float hi) {
    unsigned int r;
    asm("v_cvt_pk_bf16_f32 %0, %1, %2" : "=v"(r) : "v"(lo), "v"(hi));
    return r;
}
// 64-col bf16 tile: 8 16B-chunks/row; phys chunk p of row r holds logical p^(r&7)
#define SWZ64(row, b) ((((row) * 8) + ((b) ^ ((row) & 7))) * 8)

// ---------------- merged cast fp32 -> bf16 ----------------
__global__ void cast_all(const float4* __restrict__ X, const float4* __restrict__ Wq,
                         const float4* __restrict__ Wk, const float4* __restrict__ Wv,
                         const float4* __restrict__ Wo, ushort4* __restrict__ Xb,
                         ushort4* __restrict__ Wqkvb, ushort4* __restrict__ Wob) {
    int i = blockIdx.x * blockDim.x + threadIdx.x;
    const float4* src;
    ushort4* dst;
    int off;
    if (i < 1048576) { src = X; dst = Xb; off = i; }
    else if (i < 1310720) { src = Wq; dst = Wqkvb; off = i - 1048576; }
    else if (i < 1572864) { src = Wk; dst = Wqkvb + 262144; off = i - 1310720; }
    else if (i < 1835008) { src = Wv; dst = Wqkvb + 524288; off = i - 1572864; }
    else { src = Wo; dst = Wob; off = i - 1835008; }
    float4 v = src[off];
    ushort4 o;
    o.x = f2bf(v.x); o.y = f2bf(v.y); o.z = f2bf(v.z); o.w = f2bf(v.w);
    dst[off] = o;
}

// ---------------- GEMM 128 x TN, BK=64, 32x32x16 MFMA: C = A * B^T ---------
// 256 thr / 4 waves. TN=128: wave owns 64x64 (2x2 accs). TN=64: 32x64 (1x2).
// A/B frag: outer = lane&31, k = ks*16 + (lane>>5)*8 + e  (chunk ks*2+lh).
// C/D: col(N) = lane&31, row(M) = (r&3) + 8*(r>>2) + 4*(lane>>5).
// XCD-aware bijective block swizzle (nwg % 8 == 0 for both launches).
template <int TN, int OUT_BF16>
__global__ __launch_bounds__(256) void gemm_tile32(
    const unsigned short* __restrict__ A, const unsigned short* __restrict__ B,
    void* __restrict__ Cout, int M, int N, int K) {
    __shared__ unsigned short As[128 * 64];
    __shared__ unsigned short Bs[TN * 64];
    const int nwg = gridDim.x * gridDim.y;
    const int bid = blockIdx.y * gridDim.x + blockIdx.x;
    const int swz = (bid & 7) * (nwg >> 3) + (bid >> 3);
    const int m0 = (swz / gridDim.x) * 128, n0 = (swz % gridDim.x) * TN;
    const int t = threadIdx.x;
    const int lane = t & 63, wave = t >> 6;
    const int l31 = lane & 31, lh = lane >> 5;
    constexpr int MI = (TN == 128) ? 2 : 1; // 32-row blocks per wave
    constexpr int NI = 2;                   // 32-col blocks per wave
    const int wr = (TN == 128) ? (wave >> 1) * 64 : wave * 32;
    const int wc = (TN == 128) ? (wave & 1) * 64 : 0;

    f32x16 acc[MI][NI];
#pragma unroll
    for (int mi = 0; mi < MI; ++mi)
#pragma unroll
        for (int ni = 0; ni < NI; ++ni)
#pragma unroll
            for (int r = 0; r < 16; ++r) acc[mi][ni][r] = 0.f;

    for (int k0 = 0; k0 < K; k0 += 64) {
#pragma unroll
        for (int i = 0; i < 4; ++i) { // A: 1024 chunks
            int ch = i * 256 + t;
            int r = ch >> 3, b = (ch & 7) ^ (r & 7);
            async16(A + (size_t)(m0 + r) * K + k0 + b * 8, (char*)As + ch * 16);
        }
#pragma unroll
        for (int i = 0; i < TN / 32; ++i) { // B: TN*8 chunks
            int ch = i * 256 + t;
            int r = ch >> 3, b = (ch & 7) ^ (r & 7);
            async16(B + (size_t)(n0 + r) * K + k0 + b * 8, (char*)Bs + ch * 16);
        }
        __syncthreads();
#pragma unroll
        for (int ks = 0; ks < 4; ++ks) { // K sub-steps of 16
            bf16x8 af[MI], bfr[NI];
#pragma unroll
            for (int mi = 0; mi < MI; ++mi)
                af[mi] = *(const bf16x8*)&As[SWZ64(wr + mi * 32 + l31, ks * 2 + lh)];
#pragma unroll
            for (int ni = 0; ni < NI; ++ni)
                bfr[ni] = *(const bf16x8*)&Bs[SWZ64(wc + ni * 32 + l31, ks * 2 + lh)];
#pragma unroll
            for (int mi = 0; mi < MI; ++mi)
#pragma unroll
                for (int ni = 0; ni < NI; ++ni)
                    acc[mi][ni] = __builtin_amdgcn_mfma_f32_32x32x16_bf16(
                        af[mi], bfr[ni], acc[mi][ni], 0, 0, 0);
        }
        __syncthreads();
    }
#pragma unroll
    for (int mi = 0; mi < MI; ++mi)
#pragma unroll
        for (int ni = 0; ni < NI; ++ni)
#pragma unroll
            for (int rg = 0; rg < 4; ++rg)
#pragma unroll
                for (int c = 0; c < 4; ++c) {
                    int gm = m0 + wr + mi * 32 + 8 * rg + 4 * lh + c;
                    int gn = n0 + wc + ni * 32 + l31;
                    float v = acc[mi][ni][rg * 4 + c];
                    if (OUT_BF16)
                        ((unsigned short*)Cout)[(size_t)gm * N + gn] = f2bf(v);
                    else
                        ((float*)Cout)[(size_t)gm * N + gn] = v;
                }
}

// ---------------- merged RoPE Q/K + V transpose ----------------
// bx < 4096: rope (4 elems/thread). bx >= 4096: vtrans 64x64 tile.
// Q outputs are pre-scaled by 1/sqrt(dk)*log2e (folded into cos/sin).
__global__ __launch_bounds__(256) void rope_vt(const unsigned short* __restrict__ QKV,
                                               unsigned short* __restrict__ Qr,
                                               unsigned short* __restrict__ Kr,
                                               unsigned short* __restrict__ Vt) {
    __shared__ unsigned short T[64][80];
    const int bx = blockIdx.x;
    const int t = threadIdx.x;
    if (bx < 4096) { // ---- RoPE ----
        int tid = bx * 256 + t;
        int bs = tid >> 8;
        int p4 = tid & 255;
        int b = bs >> 11, spos = bs & 2047;
        int h = p4 >> 4, dd = (p4 & 15) * 4;
        float sn0, cs0, sn1, cs1;
        {
            float if0 = __expf(-(float)dd * (9.210340371976184f / 64.0f));
            float if1 = __expf(-(float)(dd + 2) * (9.210340371976184f / 64.0f));
            __sincosf((float)spos * if0, &sn0, &cs0);
            __sincosf((float)spos * if1, &sn1, &cs1);
        }
        const float SCQ = 0.125f * LOG2E;
        float cs0q = cs0 * SCQ, sn0q = sn0 * SCQ;
        float cs1q = cs1 * SCQ, sn1q = sn1 * SCQ;
        size_t src = (size_t)bs * 3072 + h * 64 + dd;
        ushort4 qw = *(const ushort4*)&QKV[src];
        ushort4 kw = *(const ushort4*)&QKV[src + 1024];
        ushort4 qo_, ko_;
        float e = bf2f(qw.x), o = bf2f(qw.y);
        qo_.x = f2bf(e * cs0q - o * sn0q); qo_.y = f2bf(o * cs0q + e * sn0q);
        e = bf2f(qw.z); o = bf2f(qw.w);
        qo_.z = f2bf(e * cs1q - o * sn1q); qo_.w = f2bf(o * cs1q + e * sn1q);
        e = bf2f(kw.x); o = bf2f(kw.y);
        ko_.x = f2bf(e * cs0 - o * sn0); ko_.y = f2bf(o * cs0 + e * sn0);
        e = bf2f(kw.z); o = bf2f(kw.w);
        ko_.z = f2bf(e * cs1 - o * sn1); ko_.w = f2bf(o * cs1 + e * sn1);
        size_t qb = (((size_t)(b * NUM_HEADS + h) * SEQ + spos) * DK + dd);
        *(ushort4*)&Qr[qb] = qo_;
        *(ushort4*)&Kr[qb] = ko_;
    } else { // ---- V transpose ----
        int idx = bx - 4096;
        const int s0 = (idx & 31) * 64, bh = idx >> 5;
        const int b = bh >> 4, h = bh & 15;
#pragma unroll
        for (int i = 0; i < 2; ++i) {
            int ch = i * 256 + t;
            int row = ch >> 3, bc = ch & 7;
            *(int4*)&T[row][bc * 8] =
                *(const int4*)&QKV[(size_t)(b * SEQ + s0 + row) * 3072 + 2048 + h * 64 + bc * 8];
        }
        __syncthreads();
#pragma unroll
        for (int i = 0; i < 2; ++i) {
            int ch = i * 256 + t;
            int d = ch >> 3, sb = ch & 7;
            unsigned short tmp[8];
#pragma unroll
            for (int j = 0; j < 8; ++j) tmp[j] = T[sb * 8 + j][d];
            *(int4*)&Vt[(size_t)bh * DK * SEQ + (size_t)d * SEQ + s0 + sb * 8] = *(int4*)tmp;
        }
    }
}

// ---------------- Flash attention v12: v10 + V direct from L2 --------------
// Grid (32 bh, 32 qt), qt = 31 - by (LPT). LDS 16.9 KB (K dbuf only).
// Wave (wq = w>>1, wd = w&1): swapped QK^T for q-half wq over its OWN j-block
// wd, softmax+fragments in-register, PV of that j-half for BOTH d-blocks.
// V fragments are read straight from global (Vt is L2/L3-resident; staging
// V in LDS was pure overhead -- m169 precedent). Same bytes as the staged
// path: Vg + d*SEQ + j0 + c*8, c = wd*4 + {0,2} + lh.
// O = sum of wd-pair partials via one LDS exchange at the epilogue.
// C/D map: col = lane&31 (N), row = crow(r,lh) = (r&3)+8*(r>>2)+4*(lane>>5).
__global__ __launch_bounds__(256, 4) void flash_attn12(
    const unsigned short* __restrict__ Qr, const unsigned short* __restrict__ Kr,
    const unsigned short* __restrict__ Vt, unsigned short* __restrict__ Att) {
    __shared__ unsigned short Ks[2][64 * 64]; // 16 KB K dbuf; epilogue: O-exchange
    __shared__ float LS[128];                 // per-wave lsum exchange (512 B)
    const int bh = blockIdx.x;
    const int qt = 31 - (int)blockIdx.y;
    const int t = threadIdx.x;
    const int lane = t & 63, wave = t >> 6;
    const int l31 = lane & 31, lh = lane >> 5;
    const int wq = wave >> 1, wd = wave & 1;
    const size_t qkbase = (size_t)bh * SEQ * DK;
    const unsigned short* Kg = Kr + qkbase;
    const unsigned short* Vg = Vt + (size_t)bh * DK * SEQ;
    const int qg = qt * 64 + wq * 32 + l31; // this lane's q (column of C)

    // Q fragments (pre-scaled in rope_vt): B-operand, n=q=l31, k=16kk+8lh+e
    bf16x8 aq[4];
#pragma unroll
    for (int kk = 0; kk < 4; ++kk)
        aq[kk] = *(const bf16x8*)&Qr[qkbase + (size_t)qg * DK + kk * 16 + lh * 8];

    f32x16 acc0, acc1; // O^T partials (j-block wd only): d-block 0 / 1
#pragma unroll
    for (int r = 0; r < 16; ++r) { acc0[r] = 0.f; acc1[r] = 0.f; }
    float la[4] = {0.f, 0.f, 0.f, 0.f}; // softmax partial sums (chain-split)

    // stage K tile 0 into buffer 0 (512 chunks, 2/thread)
#pragma unroll
    for (int i = 0; i < 2; ++i) {
        int ch = i * 256 + t;
        int row = ch >> 3, sb = (ch & 7) ^ (row & 7);
        async16(Kg + (size_t)row * DK + sb * 8, (char*)Ks[0] + ch * 16);
    }

    for (int jt = 0; jt <= qt; ++jt) {
        __syncthreads(); // stage(jt) visible; compute(jt-1) done
        const int cur = jt & 1;
        if (jt < qt) { // prefetch next K tile (overlaps compute)
            const int j1 = (jt + 1) * 64;
#pragma unroll
            for (int i = 0; i < 2; ++i) {
                int ch = i * 256 + t;
                int row = ch >> 3, sb = (ch & 7) ^ (row & 7);
                async16(Kg + (size_t)(j1 + row) * DK + sb * 8, (char*)Ks[cur ^ 1] + ch * 16);
            }
        }
        const unsigned short* Kt = Ks[cur];
        const int j0 = jt * 64;
        const bool diag = (jt == qt);
        if (diag && wd > wq) continue; // j-block entirely above diagonal

        // ---- V fragments direct from global (independent of QK^T chain) ----
        const unsigned short* Vj = Vg + j0;
        bf16x8 vf0 = *(const bf16x8*)&Vj[(size_t)l31 * SEQ + (wd * 4 + lh) * 8];
        bf16x8 vf1 = *(const bf16x8*)&Vj[(size_t)l31 * SEQ + (wd * 4 + 2 + lh) * 8];
        bf16x8 vf2 = *(const bf16x8*)&Vj[(size_t)(32 + l31) * SEQ + (wd * 4 + lh) * 8];
        bf16x8 vf3 = *(const bf16x8*)&Vj[(size_t)(32 + l31) * SEQ + (wd * 4 + 2 + lh) * 8];

        // ---- swapped QK^T: col = q = l31, row = j = 32*wd + crow(r,lh) ----
        f32x16 s;
#pragma unroll
        for (int r = 0; r < 16; ++r) s[r] = 0.f;
        __builtin_amdgcn_s_setprio(1);
#pragma unroll
        for (int kk = 0; kk < 4; ++kk) {
            bf16x8 kf = *(const bf16x8*)&Kt[SWZ64(wd * 32 + l31, kk * 2 + lh)];
            s = __builtin_amdgcn_mfma_f32_32x32x16_bf16(kf, aq[kk], s, 0, 0, 0);
        }
        __builtin_amdgcn_s_setprio(0);
        if (diag && wd == wq) { // straddle: mask j > q <=> crow > l31
#pragma unroll
            for (int r = 0; r < 16; ++r) {
                int crow = (r & 3) + 8 * (r >> 2) + 4 * lh;
                if (crow > l31) s[r] = -1e30f;
            }
        }

        // ---- p = exp2(s - FIXM); accumulate column sum ----
#pragma unroll
        for (int r = 0; r < 16; ++r) {
            s[r] = __builtin_amdgcn_exp2f(s[r] - FIXM);
            la[r & 3] += s[r];
        }

        // ---- PV B-fragments in-register (cvt_pk + permlane32_swap) ----
        // frA = j-chunk 2wd (rows 0..15 of s), frB = j-chunk 2wd+1 (rows 16..31)
        bf16x8 frA, frB;
        {
            unsigned int u0 = cvtpk(s[0], s[1]), v0 = cvtpk(s[4], s[5]);
            unsigned int u1 = cvtpk(s[2], s[3]), v1 = cvtpk(s[6], s[7]);
            asm("v_permlane32_swap_b32 %0, %1" : "+v"(u0), "+v"(v0));
            asm("v_permlane32_swap_b32 %0, %1" : "+v"(u1), "+v"(v1));
            uint4 w = {u0, u1, v0, v1};
            frA = *(bf16x8*)&w;
            unsigned int u2 = cvtpk(s[8], s[9]), v2 = cvtpk(s[12], s[13]);
            unsigned int u3 = cvtpk(s[10], s[11]), v3 = cvtpk(s[14], s[15]);
            asm("v_permlane32_swap_b32 %0, %1" : "+v"(u2), "+v"(v2));
            asm("v_permlane32_swap_b32 %0, %1" : "+v"(u3), "+v"(v3));
            uint4 w2_ = {u2, u3, v2, v3};
            frB = *(bf16x8*)&w2_;
        }

        // ---- PV: both d-blocks, this wave's j-half (k-chunks 2wd, 2wd+1) ----
        __builtin_amdgcn_s_setprio(1);
        {
            acc0 = __builtin_amdgcn_mfma_f32_32x32x16_bf16(vf0, frA, acc0, 0, 0, 0);
            acc0 = __builtin_amdgcn_mfma_f32_32x32x16_bf16(vf1, frB, acc0, 0, 0, 0);
            acc1 = __builtin_amdgcn_mfma_f32_32x32x16_bf16(vf2, frA, acc1, 0, 0, 0);
            acc1 = __builtin_amdgcn_mfma_f32_32x32x16_bf16(vf3, frB, acc1, 0, 0, 0);
        }
        __builtin_amdgcn_s_setprio(0);
    }

    // ---- epilogue: cross-wave O reduce (wd pair) + softmax normalize ----
    float lt = (la[0] + la[1]) + (la[2] + la[3]);
    lt += __shfl_xor(lt, 32, 64); // full j-block sum for col q = l31
    __syncthreads(); // all waves done with Ks tiles
    float* SC = (float*)Ks; // 4 slots x 4 KB: [wq*2+ti][r*64+lane]
    if (wd == 0) { // outputs d-block 0; hand d-block 1 partial to partner
#pragma unroll
        for (int r = 0; r < 16; ++r) SC[(wq * 2 + 1) * 1024 + r * 64 + lane] = acc1[r];
    } else { // outputs d-block 1; hand d-block 0 partial to partner
#pragma unroll
        for (int r = 0; r < 16; ++r) SC[(wq * 2 + 0) * 1024 + r * 64 + lane] = acc0[r];
    }
    if (lane < 32) LS[wave * 32 + l31] = lt;
    __syncthreads();
    const float rl = 1.0f / (LS[(wq * 2) * 32 + l31] + LS[(wq * 2 + 1) * 32 + l31]);
    float outv[16];
    if (wd == 0) {
#pragma unroll
        for (int r = 0; r < 16; ++r)
            outv[r] = acc0[r] + SC[(wq * 2 + 0) * 1024 + r * 64 + lane];
    } else {
#pragma unroll
        for (int r = 0; r < 16; ++r)
            outv[r] = acc1[r] + SC[(wq * 2 + 1) * 1024 + r * 64 + lane];
    }

    const int b_ = bh >> 4, h_ = bh & 15;
#pragma unroll
    for (int rg = 0; rg < 4; ++rg) {
        ushort4 o;
        o.x = f2bf(outv[rg * 4 + 0] * rl);
        o.y = f2bf(outv[rg * 4 + 1] * rl);
        o.z = f2bf(outv[rg * 4 + 2] * rl);
        o.w = f2bf(outv[rg * 4 + 3] * rl);
        *(ushort4*)&Att[(size_t)(b_ * SEQ + qg) * D_MODEL + h_ * DK + wd * 32 + 8 * rg + 4 * lh] = o;
    }
}

extern "C" void kernel_launch(void* const* d_in, const int* in_sizes, int n_in,
                              void* d_out, int out_size, void* d_ws, size_t ws_size,
                              hipStream_t stream) {
    const float* X = (const float*)d_in[0];
    const float* Wq = (const float*)d_in[1];
    const float* Wk = (const float*)d_in[2];
    const float* Wv = (const float*)d_in[3];
    const float* Wo = (const float*)d_in[4];

    char* ws = (char*)d_ws;
    unsigned short* Xb     = (unsigned short*)(ws + 0);
    unsigned short* Wqkvb  = (unsigned short*)(ws + (8u << 20));
    unsigned short* Wob    = (unsigned short*)(ws + (14u << 20));
    unsigned short* QKVraw = (unsigned short*)(ws + (16u << 20));
    unsigned short* Kr     = (unsigned short*)(ws + (40u << 20));
    unsigned short* Vt     = (unsigned short*)(ws + (48u << 20));
    unsigned short* Qr     = Xb;     // alias: Xb dead after QKV GEMM
    unsigned short* Att    = QKVraw; // alias: QKVraw dead after rope_vt

    cast_all<<<8192, 256, 0, stream>>>((const float4*)X, (const float4*)Wq,
                                       (const float4*)Wk, (const float4*)Wv,
                                       (const float4*)Wo, (ushort4*)Xb,
                                       (ushort4*)Wqkvb, (ushort4*)Wob);

    // fused QKV projection: [4096 x 1024] x [3072 x 1024]^T
    gemm_tile32<128, 1><<<dim3(3072 / 128, MROWS / 128), 256, 0, stream>>>(
        Xb, Wqkvb, QKVraw, MROWS, 3072, D_MODEL);

    rope_vt<<<4096 + 1024, 256, 0, stream>>>(QKVraw, Qr, Kr, Vt);

    flash_attn12<<<dim3(BATCH * NUM_HEADS, 32), 256, 0, stream>>>(Qr, Kr, Vt, Att);

    // output projection (fp32 out), 128x64 tiles
    gemm_tile32<64, 0><<<dim3(D_MODEL / 64, MROWS / 128), 256, 0, stream>>>(
        Att, Wob, d_out, MROWS, D_MODEL, D_MODEL);
}

// Round 9
// 167.769 us; speedup vs baseline: 1.1230x; 1.1230x over previous
//
#include <hip/hip_runtime.h>
#include <stdint.h>

#define D_MODEL 1024
#define NUM_HEADS 16
#define DK 64
#define SEQ 2048
#define BATCH 2
#define MROWS (BATCH * SEQ) /* 4096 */
#define LOG2E 1.4426950408889634f
#define FIXM 14.0f /* static softmax max, base-2 domain */

typedef short bf16x8 __attribute__((ext_vector_type(8)));
typedef float f32x4 __attribute__((ext_vector_type(4)));
typedef float f32x16 __attribute__((ext_vector_type(16)));

__device__ __forceinline__ unsigned short f2bf(float f) { // RNE
    unsigned int u = __float_as_uint(f);
    u = (u + 0x7fffu + ((u >> 16) & 1u)) >> 16;
    return (unsigned short)u;
}
__device__ __forceinline__ float bf2f(unsigned short h) {
    return __uint_as_float(((unsigned int)h) << 16);
}
__device__ __forceinline__ void async16(const void* g, void* l) {
    __builtin_amdgcn_global_load_lds(
        (const __attribute__((address_space(1))) void*)g,
        (__attribute__((address_space(3))) void*)l, 16, 0, 0);
}
__device__ __forceinline__ unsigned int cvtpk(float lo, float hi) {
    unsigned int r;
    asm("v_cvt_pk_bf16_f32 %0, %1, %2" : "=v"(r) : "v"(lo), "v"(hi));
    return r;
}
// 64-col bf16 tile: 8 16B-chunks/row; phys chunk p of row r holds logical p^(r&7)
#define SWZ64(row, b) ((((row) * 8) + ((b) ^ ((row) & 7))) * 8)

// ---------------- merged cast fp32 -> bf16 ----------------
__global__ void cast_all(const float4* __restrict__ X, const float4* __restrict__ Wq,
                         const float4* __restrict__ Wk, const float4* __restrict__ Wv,
                         const float4* __restrict__ Wo, ushort4* __restrict__ Xb,
                         ushort4* __restrict__ Wqkvb, ushort4* __restrict__ Wob) {
    int i = blockIdx.x * blockDim.x + threadIdx.x;
    const float4* src;
    ushort4* dst;
    int off;
    if (i < 1048576) { src = X; dst = Xb; off = i; }
    else if (i < 1310720) { src = Wq; dst = Wqkvb; off = i - 1048576; }
    else if (i < 1572864) { src = Wk; dst = Wqkvb + 262144; off = i - 1310720; }
    else if (i < 1835008) { src = Wv; dst = Wqkvb + 524288; off = i - 1572864; }
    else { src = Wo; dst = Wob; off = i - 1835008; }
    float4 v = src[off];
    ushort4 o;
    o.x = f2bf(v.x); o.y = f2bf(v.y); o.z = f2bf(v.z); o.w = f2bf(v.w);
    dst[off] = o;
}

// ---------------- GEMM 128 x TN, BK=64, 32x32x16 MFMA: C = A * B^T ---------
// 256 thr / 4 waves. TN=128: wave owns 64x64 (2x2 accs). TN=64: 32x64 (1x2).
// A/B frag: outer = lane&31, k = ks*16 + (lane>>5)*8 + e  (chunk ks*2+lh).
// C/D: col(N) = lane&31, row(M) = (r&3) + 8*(r>>2) + 4*(lane>>5).
// XCD-aware bijective block swizzle (nwg % 8 == 0 for both launches).
template <int TN, int OUT_BF16>
__global__ __launch_bounds__(256) void gemm_tile32(
    const unsigned short* __restrict__ A, const unsigned short* __restrict__ B,
    void* __restrict__ Cout, int M, int N, int K) {
    __shared__ unsigned short As[128 * 64];
    __shared__ unsigned short Bs[TN * 64];
    const int nwg = gridDim.x * gridDim.y;
    const int bid = blockIdx.y * gridDim.x + blockIdx.x;
    const int swz = (bid & 7) * (nwg >> 3) + (bid >> 3);
    const int m0 = (swz / gridDim.x) * 128, n0 = (swz % gridDim.x) * TN;
    const int t = threadIdx.x;
    const int lane = t & 63, wave = t >> 6;
    const int l31 = lane & 31, lh = lane >> 5;
    constexpr int MI = (TN == 128) ? 2 : 1; // 32-row blocks per wave
    constexpr int NI = 2;                   // 32-col blocks per wave
    const int wr = (TN == 128) ? (wave >> 1) * 64 : wave * 32;
    const int wc = (TN == 128) ? (wave & 1) * 64 : 0;

    f32x16 acc[MI][NI];
#pragma unroll
    for (int mi = 0; mi < MI; ++mi)
#pragma unroll
        for (int ni = 0; ni < NI; ++ni)
#pragma unroll
            for (int r = 0; r < 16; ++r) acc[mi][ni][r] = 0.f;

    for (int k0 = 0; k0 < K; k0 += 64) {
#pragma unroll
        for (int i = 0; i < 4; ++i) { // A: 1024 chunks
            int ch = i * 256 + t;
            int r = ch >> 3, b = (ch & 7) ^ (r & 7);
            async16(A + (size_t)(m0 + r) * K + k0 + b * 8, (char*)As + ch * 16);
        }
#pragma unroll
        for (int i = 0; i < TN / 32; ++i) { // B: TN*8 chunks
            int ch = i * 256 + t;
            int r = ch >> 3, b = (ch & 7) ^ (r & 7);
            async16(B + (size_t)(n0 + r) * K + k0 + b * 8, (char*)Bs + ch * 16);
        }
        __syncthreads();
#pragma unroll
        for (int ks = 0; ks < 4; ++ks) { // K sub-steps of 16
            bf16x8 af[MI], bfr[NI];
#pragma unroll
            for (int mi = 0; mi < MI; ++mi)
                af[mi] = *(const bf16x8*)&As[SWZ64(wr + mi * 32 + l31, ks * 2 + lh)];
#pragma unroll
            for (int ni = 0; ni < NI; ++ni)
                bfr[ni] = *(const bf16x8*)&Bs[SWZ64(wc + ni * 32 + l31, ks * 2 + lh)];
#pragma unroll
            for (int mi = 0; mi < MI; ++mi)
#pragma unroll
                for (int ni = 0; ni < NI; ++ni)
                    acc[mi][ni] = __builtin_amdgcn_mfma_f32_32x32x16_bf16(
                        af[mi], bfr[ni], acc[mi][ni], 0, 0, 0);
        }
        __syncthreads();
    }
#pragma unroll
    for (int mi = 0; mi < MI; ++mi)
#pragma unroll
        for (int ni = 0; ni < NI; ++ni)
#pragma unroll
            for (int rg = 0; rg < 4; ++rg)
#pragma unroll
                for (int c = 0; c < 4; ++c) {
                    int gm = m0 + wr + mi * 32 + 8 * rg + 4 * lh + c;
                    int gn = n0 + wc + ni * 32 + l31;
                    float v = acc[mi][ni][rg * 4 + c];
                    if (OUT_BF16)
                        ((unsigned short*)Cout)[(size_t)gm * N + gn] = f2bf(v);
                    else
                        ((float*)Cout)[(size_t)gm * N + gn] = v;
                }
}

// ---------------- merged RoPE Q/K + V transpose ----------------
// bx < 4096: rope (4 elems/thread). bx >= 4096: vtrans 64x64 tile.
// Q outputs are pre-scaled by 1/sqrt(dk)*log2e (folded into cos/sin).
__global__ __launch_bounds__(256) void rope_vt(const unsigned short* __restrict__ QKV,
                                               unsigned short* __restrict__ Qr,
                                               unsigned short* __restrict__ Kr,
                                               unsigned short* __restrict__ Vt) {
    __shared__ unsigned short T[64][80];
    const int bx = blockIdx.x;
    const int t = threadIdx.x;
    if (bx < 4096) { // ---- RoPE ----
        int tid = bx * 256 + t;
        int bs = tid >> 8;
        int p4 = tid & 255;
        int b = bs >> 11, spos = bs & 2047;
        int h = p4 >> 4, dd = (p4 & 15) * 4;
        float sn0, cs0, sn1, cs1;
        {
            float if0 = __expf(-(float)dd * (9.210340371976184f / 64.0f));
            float if1 = __expf(-(float)(dd + 2) * (9.210340371976184f / 64.0f));
            __sincosf((float)spos * if0, &sn0, &cs0);
            __sincosf((float)spos * if1, &sn1, &cs1);
        }
        const float SCQ = 0.125f * LOG2E;
        float cs0q = cs0 * SCQ, sn0q = sn0 * SCQ;
        float cs1q = cs1 * SCQ, sn1q = sn1 * SCQ;
        size_t src = (size_t)bs * 3072 + h * 64 + dd;
        ushort4 qw = *(const ushort4*)&QKV[src];
        ushort4 kw = *(const ushort4*)&QKV[src + 1024];
        ushort4 qo_, ko_;
        float e = bf2f(qw.x), o = bf2f(qw.y);
        qo_.x = f2bf(e * cs0q - o * sn0q); qo_.y = f2bf(o * cs0q + e * sn0q);
        e = bf2f(qw.z); o = bf2f(qw.w);
        qo_.z = f2bf(e * cs1q - o * sn1q); qo_.w = f2bf(o * cs1q + e * sn1q);
        e = bf2f(kw.x); o = bf2f(kw.y);
        ko_.x = f2bf(e * cs0 - o * sn0); ko_.y = f2bf(o * cs0 + e * sn0);
        e = bf2f(kw.z); o = bf2f(kw.w);
        ko_.z = f2bf(e * cs1 - o * sn1); ko_.w = f2bf(o * cs1 + e * sn1);
        size_t qb = (((size_t)(b * NUM_HEADS + h) * SEQ + spos) * DK + dd);
        *(ushort4*)&Qr[qb] = qo_;
        *(ushort4*)&Kr[qb] = ko_;
    } else { // ---- V transpose ----
        int idx = bx - 4096;
        const int s0 = (idx & 31) * 64, bh = idx >> 5;
        const int b = bh >> 4, h = bh & 15;
#pragma unroll
        for (int i = 0; i < 2; ++i) {
            int ch = i * 256 + t;
            int row = ch >> 3, bc = ch & 7;
            *(int4*)&T[row][bc * 8] =
                *(const int4*)&QKV[(size_t)(b * SEQ + s0 + row) * 3072 + 2048 + h * 64 + bc * 8];
        }
        __syncthreads();
#pragma unroll
        for (int i = 0; i < 2; ++i) {
            int ch = i * 256 + t;
            int d = ch >> 3, sb = ch & 7;
            unsigned short tmp[8];
#pragma unroll
            for (int j = 0; j < 8; ++j) tmp[j] = T[sb * 8 + j][d];
            *(int4*)&Vt[(size_t)bh * DK * SEQ + (size_t)d * SEQ + s0 + sb * 8] = *(int4*)tmp;
        }
    }
}

// ---------------- Flash attention v13: v10 + counted-vmcnt deep prefetch ---
// Grid (32 bh, 32 qt), qt = 31 - by (LPT). LDS 40960 B exactly -> 4 blocks/CU.
// Compute identical to verified v10. Staging: K 3-deep, V 2-deep; issue order
// prologue {K0,V0,K1}, iter jt issues {V(jt+1), K(jt+2)}. Invariant at top of
// iter jt: outstanding = [K(jt), V(jt), K(jt+1)] -> s_waitcnt vmcnt(2) (never
// 0 mid-loop, T4) + lgkmcnt(0) + raw s_barrier. Fresh prefetches are never
// drained; K has 2 iters of latency cover, V has 1.
__global__ __launch_bounds__(256, 4) void flash_attn13(
    const unsigned short* __restrict__ Qr, const unsigned short* __restrict__ Kr,
    const unsigned short* __restrict__ Vt, unsigned short* __restrict__ Att) {
    __shared__ unsigned short Ks3[3][64 * 64]; // 24 KB (epilogue: O-exchange)
    __shared__ unsigned short Vs[2][64 * 64];  // 16 KB (epilogue: lsum scratch)
    const int bh = blockIdx.x;
    const int qt = 31 - (int)blockIdx.y;
    const int t = threadIdx.x;
    const int lane = t & 63, wave = t >> 6;
    const int l31 = lane & 31, lh = lane >> 5;
    const int wq = wave >> 1, wd = wave & 1;
    const size_t qkbase = (size_t)bh * SEQ * DK;
    const unsigned short* Kg = Kr + qkbase;
    const unsigned short* Vg = Vt + (size_t)bh * DK * SEQ;
    const int qg = qt * 64 + wq * 32 + l31; // this lane's q (column of C)

    // Q fragments (pre-scaled in rope_vt): B-operand, n=q=l31, k=16kk+8lh+e
    bf16x8 aq[4];
#pragma unroll
    for (int kk = 0; kk < 4; ++kk)
        aq[kk] = *(const bf16x8*)&Qr[qkbase + (size_t)qg * DK + kk * 16 + lh * 8];

    f32x16 acc0, acc1; // O^T partials (j-block wd only): d-block 0 / 1
#pragma unroll
    for (int r = 0; r < 16; ++r) { acc0[r] = 0.f; acc1[r] = 0.f; }
    float la[4] = {0.f, 0.f, 0.f, 0.f}; // softmax partial sums (chain-split)

    // prologue staging, issue order K0, V0, K1 (2 chunks/thread each)
#pragma unroll
    for (int i = 0; i < 2; ++i) {
        int ch = i * 256 + t;
        int row = ch >> 3, sb = (ch & 7) ^ (row & 7);
        async16(Kg + (size_t)row * DK + sb * 8, (char*)Ks3[0] + ch * 16);
    }
#pragma unroll
    for (int i = 0; i < 2; ++i) {
        int ch = i * 256 + t;
        int row = ch >> 3, sb = (ch & 7) ^ (row & 7);
        async16(Vg + (size_t)row * SEQ + sb * 8, (char*)Vs[0] + ch * 16);
    }
#pragma unroll
    for (int i = 0; i < 2; ++i) {
        int ch = i * 256 + t;
        int row = ch >> 3, sb = (ch & 7) ^ (row & 7);
        async16(Kg + (size_t)(64 + row) * DK + sb * 8, (char*)Ks3[1] + ch * 16);
    }

    for (int jt = 0; jt <= qt; ++jt) {
        // counted wait: K(jt),V(jt) done; K(jt+1) stays in flight (T4)
        if (jt < qt)
            asm volatile("s_waitcnt vmcnt(2) lgkmcnt(0)" ::: "memory");
        else
            asm volatile("s_waitcnt vmcnt(0) lgkmcnt(0)" ::: "memory");
        __builtin_amdgcn_s_barrier();
        __builtin_amdgcn_sched_barrier(0);

        if (jt + 1 <= qt) { // issue V(jt+1) -> Vs[(jt+1)&1] (read by jt-1, done)
            const int j1 = (jt + 1) * 64;
#pragma unroll
            for (int i = 0; i < 2; ++i) {
                int ch = i * 256 + t;
                int row = ch >> 3, sb = (ch & 7) ^ (row & 7);
                async16(Vg + (size_t)row * SEQ + j1 + sb * 8,
                        (char*)Vs[(jt + 1) & 1] + ch * 16);
            }
        }
        if (jt + 2 <= qt) { // issue K(jt+2) -> Ks3[(jt+2)%3] (read by jt-1, done)
            const int j2 = (jt + 2) * 64;
#pragma unroll
            for (int i = 0; i < 2; ++i) {
                int ch = i * 256 + t;
                int row = ch >> 3, sb = (ch & 7) ^ (row & 7);
                async16(Kg + (size_t)(j2 + row) * DK + sb * 8,
                        (char*)Ks3[(jt + 2) % 3] + ch * 16);
            }
        }
        const unsigned short* Kt = Ks3[jt % 3];
        const unsigned short* Vtile = Vs[jt & 1];
        const bool diag = (jt == qt);
        if (diag && wd > wq) continue; // j-block entirely above diagonal

        // ---- swapped QK^T: col = q = l31, row = j = 32*wd + crow(r,lh) ----
        f32x16 s;
#pragma unroll
        for (int r = 0; r < 16; ++r) s[r] = 0.f;
        __builtin_amdgcn_s_setprio(1);
#pragma unroll
        for (int kk = 0; kk < 4; ++kk) {
            bf16x8 kf = *(const bf16x8*)&Kt[SWZ64(wd * 32 + l31, kk * 2 + lh)];
            s = __builtin_amdgcn_mfma_f32_32x32x16_bf16(kf, aq[kk], s, 0, 0, 0);
        }
        __builtin_amdgcn_s_setprio(0);
        if (diag && wd == wq) { // straddle: mask j > q <=> crow > l31
#pragma unroll
            for (int r = 0; r < 16; ++r) {
                int crow = (r & 3) + 8 * (r >> 2) + 4 * lh;
                if (crow > l31) s[r] = -1e30f;
            }
        }

        // ---- p = exp2(s - FIXM); accumulate column sum ----
#pragma unroll
        for (int r = 0; r < 16; ++r) {
            s[r] = __builtin_amdgcn_exp2f(s[r] - FIXM);
            la[r & 3] += s[r];
        }

        // ---- PV B-fragments in-register (cvt_pk + permlane32_swap) ----
        // frA = j-chunk 2wd (rows 0..15 of s), frB = j-chunk 2wd+1 (rows 16..31)
        bf16x8 frA, frB;
        {
            unsigned int u0 = cvtpk(s[0], s[1]), v0 = cvtpk(s[4], s[5]);
            unsigned int u1 = cvtpk(s[2], s[3]), v1 = cvtpk(s[6], s[7]);
            asm("v_permlane32_swap_b32 %0, %1" : "+v"(u0), "+v"(v0));
            asm("v_permlane32_swap_b32 %0, %1" : "+v"(u1), "+v"(v1));
            uint4 w = {u0, u1, v0, v1};
            frA = *(bf16x8*)&w;
            unsigned int u2 = cvtpk(s[8], s[9]), v2 = cvtpk(s[12], s[13]);
            unsigned int u3 = cvtpk(s[10], s[11]), v3 = cvtpk(s[14], s[15]);
            asm("v_permlane32_swap_b32 %0, %1" : "+v"(u2), "+v"(v2));
            asm("v_permlane32_swap_b32 %0, %1" : "+v"(u3), "+v"(v3));
            uint4 w2_ = {u2, u3, v2, v3};
            frB = *(bf16x8*)&w2_;
        }

        // ---- PV: both d-blocks, this wave's j-half (k-chunks 2wd, 2wd+1) ----
        __builtin_amdgcn_s_setprio(1);
        {
            bf16x8 vf0 = *(const bf16x8*)&Vtile[SWZ64(l31, (wd * 2 + 0) * 2 + lh)];
            acc0 = __builtin_amdgcn_mfma_f32_32x32x16_bf16(vf0, frA, acc0, 0, 0, 0);
            bf16x8 vf1 = *(const bf16x8*)&Vtile[SWZ64(l31, (wd * 2 + 1) * 2 + lh)];
            acc0 = __builtin_amdgcn_mfma_f32_32x32x16_bf16(vf1, frB, acc0, 0, 0, 0);
            bf16x8 vf2 = *(const bf16x8*)&Vtile[SWZ64(32 + l31, (wd * 2 + 0) * 2 + lh)];
            acc1 = __builtin_amdgcn_mfma_f32_32x32x16_bf16(vf2, frA, acc1, 0, 0, 0);
            bf16x8 vf3 = *(const bf16x8*)&Vtile[SWZ64(32 + l31, (wd * 2 + 1) * 2 + lh)];
            acc1 = __builtin_amdgcn_mfma_f32_32x32x16_bf16(vf3, frB, acc1, 0, 0, 0);
        }
        __builtin_amdgcn_s_setprio(0);
    }

    // ---- epilogue: cross-wave O reduce (wd pair) + softmax normalize ----
    float lt = (la[0] + la[1]) + (la[2] + la[3]);
    lt += __shfl_xor(lt, 32, 64); // full j-block sum for col q = l31
    __syncthreads(); // all waves done with Ks3/Vs tiles (vmcnt fully drained)
    float* SC = (float*)Ks3; // 4 slots x 4 KB: [wq*2+ti][r*64+lane]
    float* LS = (float*)Vs;  // 4 x 32 floats: [wave][l31]
    if (wd == 0) { // outputs d-block 0; hand d-block 1 partial to partner
#pragma unroll
        for (int r = 0; r < 16; ++r) SC[(wq * 2 + 1) * 1024 + r * 64 + lane] = acc1[r];
    } else { // outputs d-block 1; hand d-block 0 partial to partner
#pragma unroll
        for (int r = 0; r < 16; ++r) SC[(wq * 2 + 0) * 1024 + r * 64 + lane] = acc0[r];
    }
    if (lane < 32) LS[wave * 32 + l31] = lt;
    __syncthreads();
    const float rl = 1.0f / (LS[(wq * 2) * 32 + l31] + LS[(wq * 2 + 1) * 32 + l31]);
    float outv[16];
    if (wd == 0) {
#pragma unroll
        for (int r = 0; r < 16; ++r)
            outv[r] = acc0[r] + SC[(wq * 2 + 0) * 1024 + r * 64 + lane];
    } else {
#pragma unroll
        for (int r = 0; r < 16; ++r)
            outv[r] = acc1[r] + SC[(wq * 2 + 1) * 1024 + r * 64 + lane];
    }

    const int b_ = bh >> 4, h_ = bh & 15;
#pragma unroll
    for (int rg = 0; rg < 4; ++rg) {
        ushort4 o;
        o.x = f2bf(outv[rg * 4 + 0] * rl);
        o.y = f2bf(outv[rg * 4 + 1] * rl);
        o.z = f2bf(outv[rg * 4 + 2] * rl);
        o.w = f2bf(outv[rg * 4 + 3] * rl);
        *(ushort4*)&Att[(size_t)(b_ * SEQ + qg) * D_MODEL + h_ * DK + wd * 32 + 8 * rg + 4 * lh] = o;
    }
}

extern "C" void kernel_launch(void* const* d_in, const int* in_sizes, int n_in,
                              void* d_out, int out_size, void* d_ws, size_t ws_size,
                              hipStream_t stream) {
    const float* X = (const float*)d_in[0];
    const float* Wq = (const float*)d_in[1];
    const float* Wk = (const float*)d_in[2];
    const float* Wv = (const float*)d_in[3];
    const float* Wo = (const float*)d_in[4];

    char* ws = (char*)d_ws;
    unsigned short* Xb     = (unsigned short*)(ws + 0);
    unsigned short* Wqkvb  = (unsigned short*)(ws + (8u << 20));
    unsigned short* Wob    = (unsigned short*)(ws + (14u << 20));
    unsigned short* QKVraw = (unsigned short*)(ws + (16u << 20));
    unsigned short* Kr     = (unsigned short*)(ws + (40u << 20));
    unsigned short* Vt     = (unsigned short*)(ws + (48u << 20));
    unsigned short* Qr     = Xb;     // alias: Xb dead after QKV GEMM
    unsigned short* Att    = QKVraw; // alias: QKVraw dead after rope_vt

    cast_all<<<8192, 256, 0, stream>>>((const float4*)X, (const float4*)Wq,
                                       (const float4*)Wk, (const float4*)Wv,
                                       (const float4*)Wo, (ushort4*)Xb,
                                       (ushort4*)Wqkvb, (ushort4*)Wob);

    // fused QKV projection: [4096 x 1024] x [3072 x 1024]^T
    gemm_tile32<128, 1><<<dim3(3072 / 128, MROWS / 128), 256, 0, stream>>>(
        Xb, Wqkvb, QKVraw, MROWS, 3072, D_MODEL);

    rope_vt<<<4096 + 1024, 256, 0, stream>>>(QKVraw, Qr, Kr, Vt);

    flash_attn13<<<dim3(BATCH * NUM_HEADS, 32), 256, 0, stream>>>(Qr, Kr, Vt, Att);

    // output projection (fp32 out), 128x64 tiles
    gemm_tile32<64, 0><<<dim3(D_MODEL / 64, MROWS / 128), 256, 0, stream>>>(
        Att, Wob, d_out, MROWS, D_MODEL, D_MODEL);
}